// Round 13
// baseline (70.943 us; speedup 1.0000x reference)
//
#include <hip/hip_runtime.h>

#define B_    128
#define I_    4608
#define O_    10
#define D_    16
#define NCHUNKS 2304      // I_/2
#define NIB   64          // i-blocks; 72 i = 36 chunks each
#define CPB   36          // chunks per i-block
#define CHH   2560        // halves per prepped chunk: 5 p * 64 lane * 8 (P image only)
#define PSET  20480       // floats per partial set (128*10*16)

typedef _Float16 f16x2 __attribute__((ext_vector_type(2)));
typedef _Float16 f16x4 __attribute__((ext_vector_type(4)));
typedef _Float16 f16x8 __attribute__((ext_vector_type(8)));
typedef float    f32x4 __attribute__((ext_vector_type(4)));
typedef __fp16   pk16x2 __attribute__((ext_vector_type(2)));
typedef unsigned int uint2v __attribute__((ext_vector_type(2)));

__device__ __forceinline__ f16x4 pack4(float a, float b, float c, float d) {
    union { f16x4 v; pk16x2 p[2]; } u;
    u.p[0] = __builtin_amdgcn_cvt_pkrtz(a, b);
    u.p[1] = __builtin_amdgcn_cvt_pkrtz(c, d);
    return u.v;
}
__device__ __forceinline__ f16x2 splat_h2(float a) {
    union { f16x2 v; pk16x2 p; } u;
    u.p = __builtin_amdgcn_cvt_pkrtz(a, a);
    return u.v;
}

// ---------------------------------------------------------------------------
// Prep: W [10][4608][16][8] fp32 -> P image only, lane-major f16 (R10-verified).
// pw[chunk][p][lane][8 halves]; apply A-frag: row=d (lane&15),
// K-col n=4g+j with sigma(n) -> (iloc=g&1, k=(g>>1)*4+j). o-pair per 8 halves.
// ---------------------------------------------------------------------------
__global__ __launch_bounds__(256)
void prep_kernel(const float* __restrict__ w, _Float16* __restrict__ pw)
{
    __shared__ float wch[2560];           // [o][iloc*128 + d*8 + k]
    const int c = blockIdx.x, t = threadIdx.x;
#pragma unroll
    for (int o = 0; o < O_; ++o)
        wch[o * 256 + t] = w[(long)o * (I_ * 128) + (long)c * 256 + t];
    __syncthreads();

    _Float16* dst = pw + (long)c * CHH;
#pragma unroll
    for (int kk = 0; kk < 3; ++kk) {
        const int sidx = t + kk * 256;            // 0..639 f16x4 slots
        if (sidx < 640) {
            const int hg   = sidx & 1;
            const int lane = (sidx >> 1) & 63;
            const int p    = sidx >> 7;           // 0..4
            const int r = lane & 15, g = lane >> 4;
            const int o = 2 * p + hg;
            // P: row r=d, col n=g*4+j -> (iloc=g&1, k=(g>>1)*4+j)
            const float4 gg = *(const float4*)&wch[o * 256 + (g & 1) * 128 + r * 8 + (g >> 1) * 4];
            *(f16x4*)(dst + (long)sidx * 4) = pack4(gg.x, gg.y, gg.z, gg.w);
        }
    }
}

// ---------------------------------------------------------------------------
// MFMA routing pass (R10-verified math) + double-buffered frag prefetch.
// Grid 512 = 64 ib x 8 bg, XCD-grouped. Two frag buffers fA/fB alternate over
// a fully-unrolled 5-step body (static indexing), so loads for chunk c+16
// issue at the end of the step using chunk c -> one full iteration of L2
// latency slack (was: zero prefetch distance).
// MODE 1 logits: Wt via identity-MFMA transpose; u = Wt x v; bd = in-lane dot
// + permlane32_swap; softmax over o. MODE 0: uniform c (pre=0.1 in reduce).
// End: 3-step LDS tree over waves -> parts[ib].
// ---------------------------------------------------------------------------
template<int MODE>
__global__ __launch_bounds__(512, (MODE == 1) ? 3 : 4)
void pass_kernel(const float* __restrict__ x,      // [128][4608][8]
                 const _Float16* __restrict__ pw,  // prepped P frag image
                 const float* __restrict__ v,      // [128][10][16]
                 float* __restrict__ parts)        // [NIB][128][10][16]
{
    __shared__ float red[4 * 2560];   // 40 KB

    const int tid  = threadIdx.x;
    const int lane = tid & 63;
    const int wv   = tid >> 6;
    const int bl   = lane & 15;
    const int g    = lane >> 4;
    const int u    = blockIdx.x;
    const int xcd  = u & 7, s = u >> 3;            // s: 0..63
    const int ib   = xcd * 8 + (s & 7);            // same-XCD blocks share ib range
    const int bg   = s >> 3;                       // 0..7
    const int c0   = ib * CPB;
    const int cend = c0 + CPB;
    const int iloc = g & 1, kq = g >> 1;
    const int b0   = bg * 16 + bl;

    // identity B-frag: I[K=4g+j][col=bl] = (4g+j == bl)
    f16x4 idf;
#pragma unroll
    for (int j = 0; j < 4; ++j) idf[j] = (_Float16)((bl == 4 * g + j) ? 1.f : 0.f);

    f16x4 vf[O_];
    if (MODE == 1) {
#pragma unroll
        for (int o = 0; o < O_; ++o) {
            const float4 vv = *(const float4*)(v + ((long)b0 * O_ + o) * D_ + g * 4);
            vf[o] = pack4(vv.x, vv.y, vv.z, vv.w);
        }
    }

    f32x4 S[O_];
#pragma unroll
    for (int o = 0; o < O_; ++o) S[o] = (f32x4)(0.f);

    const long lofs = (long)lane * 8;
    auto fragp = [&](int c, int p) {
        return (const f16x8*)(pw + (long)c * CHH + p * 512 + lofs);
    };
    auto xp = [&](int c) {
        return (const float4*)(x + ((long)b0 * I_ + 2 * c + iloc) * 8 + kq * 4);
    };

    const int cw = c0 + wv;
    f16x8 fA[5], fB[5];
    float4 xqA, xqB;
#pragma unroll
    for (int p = 0; p < 5; ++p) fA[p] = *fragp(cw, p);
    xqA = *xp(cw);
#pragma unroll
    for (int p = 0; p < 5; ++p) fB[p] = *fragp(cw + 8, p);
    xqB = *xp(cw + 8);

    // one step: compute chunk cc from (fU,xqU), then prefetch cc+16 into them
    auto body = [&](f16x8 (&fU)[5], float4& xqU, int cc) {
        if (cc >= cend) return;
        int cn2 = cc + 16; if (cn2 > NCHUNKS - 1) cn2 = NCHUNKS - 1;
        const float4 xq = xqU;

        float cs[O_];
        if (MODE == 1) {
            // logits: Wt = transpose(P) via identity MFMA; u = Wt x v;
            // bd = sum_k u*x (in-lane + permlane32_swap); softmax over o
#pragma unroll
            for (int p = 0; p < 5; ++p) {
                f16x4 pe, po;
                pe[0]=fU[p][0]; pe[1]=fU[p][1]; pe[2]=fU[p][2]; pe[3]=fU[p][3];
                po[0]=fU[p][4]; po[1]=fU[p][5]; po[2]=fU[p][6]; po[3]=fU[p][7];
                const f32x4 te = __builtin_amdgcn_mfma_f32_16x16x16f16(pe, idf, (f32x4)(0.f), 0, 0, 0);
                const f32x4 to = __builtin_amdgcn_mfma_f32_16x16x16f16(po, idf, (f32x4)(0.f), 0, 0, 0);
                const f16x4 ae = pack4(te[0], te[1], te[2], te[3]);
                const f16x4 ao = pack4(to[0], to[1], to[2], to[3]);
                const f32x4 ua = __builtin_amdgcn_mfma_f32_16x16x16f16(ae, vf[2*p],   (f32x4)(0.f), 0, 0, 0);
                const f32x4 ub = __builtin_amdgcn_mfma_f32_16x16x16f16(ao, vf[2*p+1], (f32x4)(0.f), 0, 0, 0);
                float d0 = ua[0] * xq.x; d0 = fmaf(ua[1], xq.y, d0);
                d0 = fmaf(ua[2], xq.z, d0); d0 = fmaf(ua[3], xq.w, d0);
                float d1 = ub[0] * xq.x; d1 = fmaf(ub[1], xq.y, d1);
                d1 = fmaf(ub[2], xq.z, d1); d1 = fmaf(ub[3], xq.w, d1);
                cs[2*p] = d0; cs[2*p+1] = d1;
            }
            float ssum = 0.f;
#pragma unroll
            for (int o = 0; o < O_; ++o) {
                const unsigned int tt = __float_as_uint(cs[o]);
                const uint2v sw = __builtin_amdgcn_permlane32_swap(tt, tt, false, false);
                const float e = __expf(__uint_as_float(sw[0]) + __uint_as_float(sw[1]));
                cs[o] = e; ssum += e;
            }
            const float inv = 1.f / ssum;
#pragma unroll
            for (int o = 0; o < O_; ++o) cs[o] *= inv;
        }

        union F4 { f16x4 v; f16x2 h[2]; };
        F4 xh;
        xh.v = pack4(xq.x, xq.y, xq.z, xq.w);
#pragma unroll
        for (int p = 0; p < 5; ++p) {
            f16x4 pe, po;
            pe[0]=fU[p][0]; pe[1]=fU[p][1]; pe[2]=fU[p][2]; pe[3]=fU[p][3];
            po[0]=fU[p][4]; po[1]=fU[p][5]; po[2]=fU[p][6]; po[3]=fU[p][7];
            F4 ye, yo;
            if (MODE == 0) { ye = xh; yo = xh; }
            else {
                const f16x2 ce = splat_h2(cs[2*p]);
                const f16x2 co = splat_h2(cs[2*p+1]);
                ye.h[0] = xh.h[0] * ce; ye.h[1] = xh.h[1] * ce;
                yo.h[0] = xh.h[0] * co; yo.h[1] = xh.h[1] * co;
            }
            S[2*p]   = __builtin_amdgcn_mfma_f32_16x16x16f16(pe, ye.v, S[2*p],   0, 0, 0);
            S[2*p+1] = __builtin_amdgcn_mfma_f32_16x16x16f16(po, yo.v, S[2*p+1], 0, 0, 0);
        }

        // prefetch chunk cc+16 into the buffer just freed (one-iter slack)
#pragma unroll
        for (int p = 0; p < 5; ++p) fU[p] = *fragp(cn2, p);
        xqU = *xp(cn2);
    };

    body(fA, xqA, cw);
    body(fB, xqB, cw + 8);
    body(fA, xqA, cw + 16);
    body(fB, xqB, cw + 24);
    body(fA, xqA, cw + 32);

    // ---- inter-wave tree reduction (waves covered disjoint chunks) ----
    auto slot = [&](int w, int o) {
        return &red[w * 2560 + o * 256 + lane * 4];
    };
#define TREE_WR(WSRC)                                                       \
    if (wv >= WSRC && wv < 2 * WSRC) {                                      \
        _Pragma("unroll") for (int o = 0; o < O_; ++o)                      \
            *(f32x4*)slot(wv - WSRC, o) = S[o];                             \
    }                                                                       \
    __syncthreads();                                                        \
    if (wv < WSRC) {                                                        \
        _Pragma("unroll") for (int o = 0; o < O_; ++o)                      \
            S[o] += *(f32x4*)slot(wv, o);                                   \
    }                                                                       \
    __syncthreads();

    TREE_WR(4)
    TREE_WR(2)
    TREE_WR(1)
#undef TREE_WR

    if (wv == 0) {
#pragma unroll
        for (int o = 0; o < O_; ++o) {
            float* pp = parts + (long)ib * PSET + ((long)b0 * O_ + o) * D_ + g * 4;
            *(f32x4*)pp = S[o];
        }
    }
}

// ---------------------------------------------------------------------------
// Reduce 64 partial sets -> s[b,o,d]; squash over d; update v_buf / out.
// Grid 1280 (one block per (b,o)).  (R6/R8/R10-verified)
// ---------------------------------------------------------------------------
__global__ __launch_bounds__(256)
void reduce_squash(const float* __restrict__ parts, float* __restrict__ v_buf,
                   float* __restrict__ out, float kscale, float pre, int mode)
{
    __shared__ float red2[4][16];
    const int tid  = threadIdx.x;
    const int lane = tid & 63;
    const int wv   = tid >> 6;
    const int g2   = blockIdx.x;        // (b*O + o)
    const int pg   = tid >> 4;          // 0..15
    const int d    = tid & 15;

    float s = 0.f;
#pragma unroll
    for (int k = 0; k < 4; ++k)
        s += parts[(long)(pg * 4 + k) * PSET + g2 * D_ + d];

    s += __shfl_xor(s, 16);
    s += __shfl_xor(s, 32);
    if (lane < 16) red2[wv][lane] = s;
    __syncthreads();

    if (tid < 16) {
        float tot = (red2[0][tid] + red2[1][tid]) + (red2[2][tid] + red2[3][tid]);
        tot *= pre;
        float n2 = tot * tot;
        n2 += __shfl_xor(n2, 1);
        n2 += __shfl_xor(n2, 2);
        n2 += __shfl_xor(n2, 4);
        n2 += __shfl_xor(n2, 8);
        const float n     = sqrtf(n2);
        const float scale = n2 / ((1.f + n2) * (n + 1e-8f));
        const float o_    = scale * tot;
        const int idx = g2 * D_ + tid;
        if (mode == 0)      { v_buf[idx] = o_;  out[idx]  = kscale * o_; }
        else if (mode == 1) { v_buf[idx] += o_; out[idx] += kscale * o_; }
        else                {                   out[idx] += kscale * o_; }
    }
}

// ---------------------------------------------------------------------------
extern "C" void kernel_launch(void* const* d_in, const int* in_sizes, int n_in,
                              void* d_out, int out_size, void* d_ws, size_t ws_size,
                              hipStream_t stream)
{
    const float* x = (const float*)d_in[0];   // [128,4608,8]
    const float* w = (const float*)d_in[1];   // [10,4608,16,8]
    float* out   = (float*)d_out;             // [128,10,16]
    float* parts = (float*)d_ws;                          // 64*80KB = 5.24 MB
    float* v_buf = parts + (long)NIB * PSET;              // 80 KB
    _Float16* pw = (_Float16*)(v_buf + B_ * O_ * D_);     // 11.8 MB P frag image

    prep_kernel<<<NCHUNKS, 256, 0, stream>>>(w, pw);

    // iter 0: c = 1/10 uniform (folded via pre=0.1)
    pass_kernel<0><<<512, 512, 0, stream>>>(x, pw, v_buf, parts);
    reduce_squash<<<1280, 256, 0, stream>>>(parts, v_buf, out, 0.3f, 0.1f, 0);

    // iter 1: b1 = <out0, xh>
    pass_kernel<1><<<512, 512, 0, stream>>>(x, pw, v_buf, parts);
    reduce_squash<<<1280, 256, 0, stream>>>(parts, v_buf, out, 0.3f, 1.0f, 1);

    // iter 2: b2 = <out0 + out1, xh>
    pass_kernel<1><<<512, 512, 0, stream>>>(x, pw, v_buf, parts);
    reduce_squash<<<1280, 256, 0, stream>>>(parts, v_buf, out, 0.4f, 1.0f, 2);
}

// Round 14
// 66.321 us; speedup vs baseline: 1.0697x; 1.0697x over previous
//
#include <hip/hip_runtime.h>

#define B_    128
#define I_    4608
#define O_    10
#define D_    16
#define NCHUNKS 2304      // I_/2
#define NIB   64          // i-blocks; 72 i = 36 chunks each
#define CPB   36          // chunks per i-block
#define CHH   2560        // halves per prepped chunk: 5 p * 64 lane * 8 (P image only)
#define PSET  20480       // floats per partial set (128*10*16)

typedef _Float16 f16x2 __attribute__((ext_vector_type(2)));
typedef _Float16 f16x4 __attribute__((ext_vector_type(4)));
typedef _Float16 f16x8 __attribute__((ext_vector_type(8)));
typedef float    f32x4 __attribute__((ext_vector_type(4)));
typedef __fp16   pk16x2 __attribute__((ext_vector_type(2)));
typedef unsigned int uint2v __attribute__((ext_vector_type(2)));

__device__ __forceinline__ f16x4 pack4(float a, float b, float c, float d) {
    union { f16x4 v; pk16x2 p[2]; } u;
    u.p[0] = __builtin_amdgcn_cvt_pkrtz(a, b);
    u.p[1] = __builtin_amdgcn_cvt_pkrtz(c, d);
    return u.v;
}
__device__ __forceinline__ f16x2 splat_h2(float a) {
    union { f16x2 v; pk16x2 p; } u;
    u.p = __builtin_amdgcn_cvt_pkrtz(a, a);
    return u.v;
}

// ---------------------------------------------------------------------------
// Prep: W [10][4608][16][8] fp32 -> P image only, lane-major f16 (R10-verified).
// pw[chunk][p][lane][8 halves]; apply A-frag: row=d (lane&15),
// K-col n=4g+j with sigma(n) -> (iloc=g&1, k=(g>>1)*4+j). o-pair per 8 halves.
// ---------------------------------------------------------------------------
__global__ __launch_bounds__(256)
void prep_kernel(const float* __restrict__ w, _Float16* __restrict__ pw)
{
    __shared__ float wch[2560];           // [o][iloc*128 + d*8 + k]
    const int c = blockIdx.x, t = threadIdx.x;
#pragma unroll
    for (int o = 0; o < O_; ++o)
        wch[o * 256 + t] = w[(long)o * (I_ * 128) + (long)c * 256 + t];
    __syncthreads();

    _Float16* dst = pw + (long)c * CHH;
#pragma unroll
    for (int kk = 0; kk < 3; ++kk) {
        const int sidx = t + kk * 256;            // 0..639 f16x4 slots
        if (sidx < 640) {
            const int hg   = sidx & 1;
            const int lane = (sidx >> 1) & 63;
            const int p    = sidx >> 7;           // 0..4
            const int r = lane & 15, g = lane >> 4;
            const int o = 2 * p + hg;
            // P: row r=d, col n=g*4+j -> (iloc=g&1, k=(g>>1)*4+j)
            const float4 gg = *(const float4*)&wch[o * 256 + (g & 1) * 128 + r * 8 + (g >> 1) * 4];
            *(f16x4*)(dst + (long)sidx * 4) = pack4(gg.x, gg.y, gg.z, gg.w);
        }
    }
}

// ---------------------------------------------------------------------------
// MFMA routing pass (R10-verified). Grid 512 = 64 i-blocks x 8 b-groups
// (16 b each), XCD-grouped (per-XCD set: pw 1.48 MB + x 2.36 MB < 4 MB L2).
// 2 blocks/CU. Waves process disjoint chunks c0+wv+8t; P frags direct from
// global. MODE 1 logits: Wt frag derived in-register via identity-MFMA
// transpose (mfma(P,I,0) -> Wt A-frag values, lossless f16 roundtrip), then
// u = mfma(Wt, v), bd = in-lane dot + permlane32_swap. End: 3-step LDS tree
// over waves. MODE 0: uniform c (pre=0.1 in reduce).
// ---------------------------------------------------------------------------
template<int MODE>
__global__ __launch_bounds__(512, 4)
void pass_kernel(const float* __restrict__ x,      // [128][4608][8]
                 const _Float16* __restrict__ pw,  // prepped P frag image
                 const float* __restrict__ v,      // [128][10][16]
                 float* __restrict__ parts)        // [NIB][128][10][16]
{
    __shared__ float red[4 * 2560];   // 40 KB

    const int tid  = threadIdx.x;
    const int lane = tid & 63;
    const int wv   = tid >> 6;
    const int bl   = lane & 15;
    const int g    = lane >> 4;
    const int u    = blockIdx.x;
    const int xcd  = u & 7, s = u >> 3;            // s: 0..63
    const int ib   = xcd * 8 + (s & 7);            // same-XCD blocks share ib range
    const int bg   = s >> 3;                       // 0..7
    const int c0   = ib * CPB;
    const int cend = c0 + CPB;
    const int iloc = g & 1, kq = g >> 1;
    const int b0   = bg * 16 + bl;

    // identity B-frag: I[K=4g+j][col=bl] = (4g+j == bl)
    f16x4 idf;
#pragma unroll
    for (int j = 0; j < 4; ++j) idf[j] = (_Float16)((bl == 4 * g + j) ? 1.f : 0.f);

    f16x4 vf[O_];
    if (MODE == 1) {
#pragma unroll
        for (int o = 0; o < O_; ++o) {
            const float4 vv = *(const float4*)(v + ((long)b0 * O_ + o) * D_ + g * 4);
            vf[o] = pack4(vv.x, vv.y, vv.z, vv.w);
        }
    }

    f32x4 S[O_];
#pragma unroll
    for (int o = 0; o < O_; ++o) S[o] = (f32x4)(0.f);

    const long lofs = (long)lane * 8;
    auto fragp = [&](int c, int p) {
        return (const f16x8*)(pw + (long)c * CHH + p * 512 + lofs);
    };
    auto xp = [&](int c) {
        return (const float4*)(x + ((long)b0 * I_ + 2 * c + iloc) * 8 + kq * 4);
    };

    int c = c0 + wv;
    f16x8 f1[5];
    float4 xqC, xqN;
#pragma unroll
    for (int p = 0; p < 5; ++p) f1[p] = *fragp(c, p);
    xqC = *xp(c);

#pragma unroll
    for (int t5 = 0; t5 < 5; ++t5) {
        const bool valid = (c < cend);
        int cn = c + 8; if (cn > NCHUNKS - 1) cn = NCHUNKS - 1;
        if (valid) {
            xqN = *xp(cn);

            float cs[O_];
            if (MODE == 1) {
                // logits: Wt = transpose(P) via identity MFMA; u = Wt x v;
                // bd = sum_k u*x (in-lane + permlane32_swap); softmax over o
#pragma unroll
                for (int p = 0; p < 5; ++p) {
                    f16x4 pe, po;
                    pe[0]=f1[p][0]; pe[1]=f1[p][1]; pe[2]=f1[p][2]; pe[3]=f1[p][3];
                    po[0]=f1[p][4]; po[1]=f1[p][5]; po[2]=f1[p][6]; po[3]=f1[p][7];
                    const f32x4 te = __builtin_amdgcn_mfma_f32_16x16x16f16(pe, idf, (f32x4)(0.f), 0, 0, 0);
                    const f32x4 to = __builtin_amdgcn_mfma_f32_16x16x16f16(po, idf, (f32x4)(0.f), 0, 0, 0);
                    const f16x4 ae = pack4(te[0], te[1], te[2], te[3]);
                    const f16x4 ao = pack4(to[0], to[1], to[2], to[3]);
                    const f32x4 ua = __builtin_amdgcn_mfma_f32_16x16x16f16(ae, vf[2*p],   (f32x4)(0.f), 0, 0, 0);
                    const f32x4 ub = __builtin_amdgcn_mfma_f32_16x16x16f16(ao, vf[2*p+1], (f32x4)(0.f), 0, 0, 0);
                    float d0 = ua[0] * xqC.x; d0 = fmaf(ua[1], xqC.y, d0);
                    d0 = fmaf(ua[2], xqC.z, d0); d0 = fmaf(ua[3], xqC.w, d0);
                    float d1 = ub[0] * xqC.x; d1 = fmaf(ub[1], xqC.y, d1);
                    d1 = fmaf(ub[2], xqC.z, d1); d1 = fmaf(ub[3], xqC.w, d1);
                    cs[2*p] = d0; cs[2*p+1] = d1;
                }
                float ssum = 0.f;
#pragma unroll
                for (int o = 0; o < O_; ++o) {
                    const unsigned int tt = __float_as_uint(cs[o]);
                    const uint2v sw = __builtin_amdgcn_permlane32_swap(tt, tt, false, false);
                    const float e = __expf(__uint_as_float(sw[0]) + __uint_as_float(sw[1]));
                    cs[o] = e; ssum += e;
                }
                const float inv = 1.f / ssum;
#pragma unroll
                for (int o = 0; o < O_; ++o) cs[o] *= inv;
            }

            union F4 { f16x4 v; f16x2 h[2]; };
            F4 xh;
            xh.v = pack4(xqC.x, xqC.y, xqC.z, xqC.w);
#pragma unroll
            for (int p = 0; p < 5; ++p) {
                f16x4 pe, po;
                pe[0]=f1[p][0]; pe[1]=f1[p][1]; pe[2]=f1[p][2]; pe[3]=f1[p][3];
                po[0]=f1[p][4]; po[1]=f1[p][5]; po[2]=f1[p][6]; po[3]=f1[p][7];
                F4 ye, yo;
                if (MODE == 0) { ye = xh; yo = xh; }
                else {
                    const f16x2 ce = splat_h2(cs[2*p]);
                    const f16x2 co = splat_h2(cs[2*p+1]);
                    ye.h[0] = xh.h[0] * ce; ye.h[1] = xh.h[1] * ce;
                    yo.h[0] = xh.h[0] * co; yo.h[1] = xh.h[1] * co;
                }
                S[2*p]   = __builtin_amdgcn_mfma_f32_16x16x16f16(pe, ye.v, S[2*p],   0, 0, 0);
                S[2*p+1] = __builtin_amdgcn_mfma_f32_16x16x16f16(po, yo.v, S[2*p+1], 0, 0, 0);
            }
#pragma unroll
            for (int p = 0; p < 5; ++p) f1[p] = *fragp(cn, p);
            xqC = xqN;
        }
        c += 8;
    }

    // ---- inter-wave tree reduction (waves covered disjoint chunks) ----
    auto slot = [&](int w, int o) {
        return &red[w * 2560 + o * 256 + lane * 4];
    };
#define TREE_WR(WSRC)                                                       \
    if (wv >= WSRC && wv < 2 * WSRC) {                                      \
        _Pragma("unroll") for (int o = 0; o < O_; ++o)                      \
            *(f32x4*)slot(wv - WSRC, o) = S[o];                             \
    }                                                                       \
    __syncthreads();                                                        \
    if (wv < WSRC) {                                                        \
        _Pragma("unroll") for (int o = 0; o < O_; ++o)                      \
            S[o] += *(f32x4*)slot(wv, o);                                   \
    }                                                                       \
    __syncthreads();

    TREE_WR(4)
    TREE_WR(2)
    TREE_WR(1)
#undef TREE_WR

    if (wv == 0) {
#pragma unroll
        for (int o = 0; o < O_; ++o) {
            float* pp = parts + (long)ib * PSET + ((long)b0 * O_ + o) * D_ + g * 4;
            *(f32x4*)pp = S[o];
        }
    }
}

// ---------------------------------------------------------------------------
// Reduce 64 partial sets -> s[b,o,d]; squash over d; update v_buf / out.
// Grid 1280 (one block per (b,o)).  (R6/R8/R10-verified)
// ---------------------------------------------------------------------------
__global__ __launch_bounds__(256)
void reduce_squash(const float* __restrict__ parts, float* __restrict__ v_buf,
                   float* __restrict__ out, float kscale, float pre, int mode)
{
    __shared__ float red2[4][16];
    const int tid  = threadIdx.x;
    const int lane = tid & 63;
    const int wv   = tid >> 6;
    const int g2   = blockIdx.x;        // (b*O + o)
    const int pg   = tid >> 4;          // 0..15
    const int d    = tid & 15;

    float s = 0.f;
#pragma unroll
    for (int k = 0; k < 4; ++k)
        s += parts[(long)(pg * 4 + k) * PSET + g2 * D_ + d];

    s += __shfl_xor(s, 16);
    s += __shfl_xor(s, 32);
    if (lane < 16) red2[wv][lane] = s;
    __syncthreads();

    if (tid < 16) {
        float tot = (red2[0][tid] + red2[1][tid]) + (red2[2][tid] + red2[3][tid]);
        tot *= pre;
        float n2 = tot * tot;
        n2 += __shfl_xor(n2, 1);
        n2 += __shfl_xor(n2, 2);
        n2 += __shfl_xor(n2, 4);
        n2 += __shfl_xor(n2, 8);
        const float n     = sqrtf(n2);
        const float scale = n2 / ((1.f + n2) * (n + 1e-8f));
        const float o_    = scale * tot;
        const int idx = g2 * D_ + tid;
        if (mode == 0)      { v_buf[idx] = o_;  out[idx]  = kscale * o_; }
        else if (mode == 1) { v_buf[idx] += o_; out[idx] += kscale * o_; }
        else                {                   out[idx] += kscale * o_; }
    }
}

// ---------------------------------------------------------------------------
extern "C" void kernel_launch(void* const* d_in, const int* in_sizes, int n_in,
                              void* d_out, int out_size, void* d_ws, size_t ws_size,
                              hipStream_t stream)
{
    const float* x = (const float*)d_in[0];   // [128,4608,8]
    const float* w = (const float*)d_in[1];   // [10,4608,16,8]
    float* out   = (float*)d_out;             // [128,10,16]
    float* parts = (float*)d_ws;                          // 64*80KB = 5.24 MB
    float* v_buf = parts + (long)NIB * PSET;              // 80 KB
    _Float16* pw = (_Float16*)(v_buf + B_ * O_ * D_);     // 11.8 MB P frag image

    prep_kernel<<<NCHUNKS, 256, 0, stream>>>(w, pw);

    // iter 0: c = 1/10 uniform (folded via pre=0.1)
    pass_kernel<0><<<512, 512, 0, stream>>>(x, pw, v_buf, parts);
    reduce_squash<<<1280, 256, 0, stream>>>(parts, v_buf, out, 0.3f, 0.1f, 0);

    // iter 1: b1 = <out0, xh>
    pass_kernel<1><<<512, 512, 0, stream>>>(x, pw, v_buf, parts);
    reduce_squash<<<1280, 256, 0, stream>>>(parts, v_buf, out, 0.3f, 1.0f, 1);

    // iter 2: b2 = <out0 + out1, xh>
    pass_kernel<1><<<512, 512, 0, stream>>>(x, pw, v_buf, parts);
    reduce_squash<<<1280, 256, 0, stream>>>(parts, v_buf, out, 0.4f, 1.0f, 2);
}

// Round 15
// 65.814 us; speedup vs baseline: 1.0779x; 1.0077x over previous
//
#include <hip/hip_runtime.h>

#define B_    128
#define I_    4608
#define O_    10
#define D_    16
#define NCHUNKS 2304      // I_/2
#define NIB   32          // i-blocks; 144 i = 72 chunks each
#define CPB   72          // chunks per i-block: 72/8 waves = 9 chunks/wave, no tail
#define CHH   2560        // halves per prepped chunk: 5 p * 64 lane * 8 (P image only)
#define PSET  20480       // floats per partial set (128*10*16)

typedef _Float16 f16x2 __attribute__((ext_vector_type(2)));
typedef _Float16 f16x4 __attribute__((ext_vector_type(4)));
typedef _Float16 f16x8 __attribute__((ext_vector_type(8)));
typedef float    f32x4 __attribute__((ext_vector_type(4)));
typedef __fp16   pk16x2 __attribute__((ext_vector_type(2)));
typedef unsigned int uint2v __attribute__((ext_vector_type(2)));

__device__ __forceinline__ f16x4 pack4(float a, float b, float c, float d) {
    union { f16x4 v; pk16x2 p[2]; } u;
    u.p[0] = __builtin_amdgcn_cvt_pkrtz(a, b);
    u.p[1] = __builtin_amdgcn_cvt_pkrtz(c, d);
    return u.v;
}
__device__ __forceinline__ f16x2 splat_h2(float a) {
    union { f16x2 v; pk16x2 p; } u;
    u.p = __builtin_amdgcn_cvt_pkrtz(a, a);
    return u.v;
}

// ---------------------------------------------------------------------------
// Prep: W [10][4608][16][8] fp32 -> P image only, lane-major f16 (R10-verified).
// pw[chunk][p][lane][8 halves]; apply A-frag: row=d (lane&15),
// K-col n=4g+j with sigma(n) -> (iloc=g&1, k=(g>>1)*4+j). o-pair per 8 halves.
// ---------------------------------------------------------------------------
__global__ __launch_bounds__(256)
void prep_kernel(const float* __restrict__ w, _Float16* __restrict__ pw)
{
    __shared__ float wch[2560];           // [o][iloc*128 + d*8 + k]
    const int c = blockIdx.x, t = threadIdx.x;
#pragma unroll
    for (int o = 0; o < O_; ++o)
        wch[o * 256 + t] = w[(long)o * (I_ * 128) + (long)c * 256 + t];
    __syncthreads();

    _Float16* dst = pw + (long)c * CHH;
#pragma unroll
    for (int kk = 0; kk < 3; ++kk) {
        const int sidx = t + kk * 256;            // 0..639 f16x4 slots
        if (sidx < 640) {
            const int hg   = sidx & 1;
            const int lane = (sidx >> 1) & 63;
            const int p    = sidx >> 7;           // 0..4
            const int r = lane & 15, g = lane >> 4;
            const int o = 2 * p + hg;
            // P: row r=d, col n=g*4+j -> (iloc=g&1, k=(g>>1)*4+j)
            const float4 gg = *(const float4*)&wch[o * 256 + (g & 1) * 128 + r * 8 + (g >> 1) * 4];
            *(f16x4*)(dst + (long)sidx * 4) = pack4(gg.x, gg.y, gg.z, gg.w);
        }
    }
}

// ---------------------------------------------------------------------------
// MFMA routing pass (R10-verified math). Grid 256 = 32 i-blocks x 8 b-groups
// (16 b each), XCD-grouped (per-XCD pw slice 1.48 MB + x 2.36 MB < 4 MB L2).
// 1 block/CU, 8 waves = 9 chunks/wave EXACTLY (72/8) -> no idle-wave tail,
// uniform block makespan. launch_bounds(512,2): VGPR cap 256 (headroom).
// MODE 1 logits: Wt frag via identity-MFMA transpose (lossless f16), then
// u = mfma(Wt, v), bd = in-lane dot + permlane32_swap, softmax over o.
// End: 3-step LDS tree over waves. MODE 0: uniform c (pre=0.1 in reduce).
// ---------------------------------------------------------------------------
template<int MODE>
__global__ __launch_bounds__(512, 2)
void pass_kernel(const float* __restrict__ x,      // [128][4608][8]
                 const _Float16* __restrict__ pw,  // prepped P frag image
                 const float* __restrict__ v,      // [128][10][16]
                 float* __restrict__ parts)        // [NIB][128][10][16]
{
    __shared__ float red[4 * 2560];   // 40 KB

    const int tid  = threadIdx.x;
    const int lane = tid & 63;
    const int wv   = tid >> 6;
    const int bl   = lane & 15;
    const int g    = lane >> 4;
    const int u    = blockIdx.x;
    const int xcd  = u & 7, s = u >> 3;            // s: 0..31
    const int ib   = xcd * 4 + (s & 3);            // same-XCD blocks share ib range
    const int bg   = s >> 2;                       // 0..7
    const int c0   = ib * CPB;
    const int iloc = g & 1, kq = g >> 1;
    const int b0   = bg * 16 + bl;

    // identity B-frag: I[K=4g+j][col=bl] = (4g+j == bl)
    f16x4 idf;
#pragma unroll
    for (int j = 0; j < 4; ++j) idf[j] = (_Float16)((bl == 4 * g + j) ? 1.f : 0.f);

    f16x4 vf[O_];
    if (MODE == 1) {
#pragma unroll
        for (int o = 0; o < O_; ++o) {
            const float4 vv = *(const float4*)(v + ((long)b0 * O_ + o) * D_ + g * 4);
            vf[o] = pack4(vv.x, vv.y, vv.z, vv.w);
        }
    }

    f32x4 S[O_];
#pragma unroll
    for (int o = 0; o < O_; ++o) S[o] = (f32x4)(0.f);

    const long lofs = (long)lane * 8;
    auto fragp = [&](int c, int p) {
        return (const f16x8*)(pw + (long)c * CHH + p * 512 + lofs);
    };
    auto xp = [&](int c) {
        return (const float4*)(x + ((long)b0 * I_ + 2 * c + iloc) * 8 + kq * 4);
    };

    int c = c0 + wv;
    f16x8 f1[5];
    float4 xqC, xqN;
#pragma unroll
    for (int p = 0; p < 5; ++p) f1[p] = *fragp(c, p);
    xqC = *xp(c);

    for (int t5 = 0; t5 < 9; ++t5) {
        int cn = c + 8; if (cn > NCHUNKS - 1) cn = NCHUNKS - 1;
        xqN = *xp(cn);

        float cs[O_];
        if (MODE == 1) {
            // logits: Wt = transpose(P) via identity MFMA; u = Wt x v;
            // bd = sum_k u*x (in-lane + permlane32_swap); softmax over o
#pragma unroll
            for (int p = 0; p < 5; ++p) {
                f16x4 pe, po;
                pe[0]=f1[p][0]; pe[1]=f1[p][1]; pe[2]=f1[p][2]; pe[3]=f1[p][3];
                po[0]=f1[p][4]; po[1]=f1[p][5]; po[2]=f1[p][6]; po[3]=f1[p][7];
                const f32x4 te = __builtin_amdgcn_mfma_f32_16x16x16f16(pe, idf, (f32x4)(0.f), 0, 0, 0);
                const f32x4 to = __builtin_amdgcn_mfma_f32_16x16x16f16(po, idf, (f32x4)(0.f), 0, 0, 0);
                const f16x4 ae = pack4(te[0], te[1], te[2], te[3]);
                const f16x4 ao = pack4(to[0], to[1], to[2], to[3]);
                const f32x4 ua = __builtin_amdgcn_mfma_f32_16x16x16f16(ae, vf[2*p],   (f32x4)(0.f), 0, 0, 0);
                const f32x4 ub = __builtin_amdgcn_mfma_f32_16x16x16f16(ao, vf[2*p+1], (f32x4)(0.f), 0, 0, 0);
                float d0 = ua[0] * xqC.x; d0 = fmaf(ua[1], xqC.y, d0);
                d0 = fmaf(ua[2], xqC.z, d0); d0 = fmaf(ua[3], xqC.w, d0);
                float d1 = ub[0] * xqC.x; d1 = fmaf(ub[1], xqC.y, d1);
                d1 = fmaf(ub[2], xqC.z, d1); d1 = fmaf(ub[3], xqC.w, d1);
                cs[2*p] = d0; cs[2*p+1] = d1;
            }
            float ssum = 0.f;
#pragma unroll
            for (int o = 0; o < O_; ++o) {
                const unsigned int tt = __float_as_uint(cs[o]);
                const uint2v sw = __builtin_amdgcn_permlane32_swap(tt, tt, false, false);
                const float e = __expf(__uint_as_float(sw[0]) + __uint_as_float(sw[1]));
                cs[o] = e; ssum += e;
            }
            const float inv = 1.f / ssum;
#pragma unroll
            for (int o = 0; o < O_; ++o) cs[o] *= inv;
        }

        union F4 { f16x4 v; f16x2 h[2]; };
        F4 xh;
        xh.v = pack4(xqC.x, xqC.y, xqC.z, xqC.w);
#pragma unroll
        for (int p = 0; p < 5; ++p) {
            f16x4 pe, po;
            pe[0]=f1[p][0]; pe[1]=f1[p][1]; pe[2]=f1[p][2]; pe[3]=f1[p][3];
            po[0]=f1[p][4]; po[1]=f1[p][5]; po[2]=f1[p][6]; po[3]=f1[p][7];
            F4 ye, yo;
            if (MODE == 0) { ye = xh; yo = xh; }
            else {
                const f16x2 ce = splat_h2(cs[2*p]);
                const f16x2 co = splat_h2(cs[2*p+1]);
                ye.h[0] = xh.h[0] * ce; ye.h[1] = xh.h[1] * ce;
                yo.h[0] = xh.h[0] * co; yo.h[1] = xh.h[1] * co;
            }
            S[2*p]   = __builtin_amdgcn_mfma_f32_16x16x16f16(pe, ye.v, S[2*p],   0, 0, 0);
            S[2*p+1] = __builtin_amdgcn_mfma_f32_16x16x16f16(po, yo.v, S[2*p+1], 0, 0, 0);
        }
#pragma unroll
        for (int p = 0; p < 5; ++p) f1[p] = *fragp(cn, p);
        xqC = xqN;
        c += 8;
    }

    // ---- inter-wave tree reduction (waves covered disjoint chunks) ----
    auto slot = [&](int w, int o) {
        return &red[w * 2560 + o * 256 + lane * 4];
    };
#define TREE_WR(WSRC)                                                       \
    if (wv >= WSRC && wv < 2 * WSRC) {                                      \
        _Pragma("unroll") for (int o = 0; o < O_; ++o)                      \
            *(f32x4*)slot(wv - WSRC, o) = S[o];                             \
    }                                                                       \
    __syncthreads();                                                        \
    if (wv < WSRC) {                                                        \
        _Pragma("unroll") for (int o = 0; o < O_; ++o)                      \
            S[o] += *(f32x4*)slot(wv, o);                                   \
    }                                                                       \
    __syncthreads();

    TREE_WR(4)
    TREE_WR(2)
    TREE_WR(1)
#undef TREE_WR

    if (wv == 0) {
#pragma unroll
        for (int o = 0; o < O_; ++o) {
            float* pp = parts + (long)ib * PSET + ((long)b0 * O_ + o) * D_ + g * 4;
            *(f32x4*)pp = S[o];
        }
    }
}

// ---------------------------------------------------------------------------
// Reduce 32 partial sets -> s[b,o,d]; squash over d; update v_buf / out.
// Grid 1280 (one block per (b,o)).
// ---------------------------------------------------------------------------
__global__ __launch_bounds__(256)
void reduce_squash(const float* __restrict__ parts, float* __restrict__ v_buf,
                   float* __restrict__ out, float kscale, float pre, int mode)
{
    __shared__ float red2[4][16];
    const int tid  = threadIdx.x;
    const int lane = tid & 63;
    const int wv   = tid >> 6;
    const int g2   = blockIdx.x;        // (b*O + o)
    const int pg   = tid >> 4;          // 0..15
    const int d    = tid & 15;

    float s = 0.f;
#pragma unroll
    for (int k = 0; k < 2; ++k)
        s += parts[(long)(pg * 2 + k) * PSET + g2 * D_ + d];

    s += __shfl_xor(s, 16);
    s += __shfl_xor(s, 32);
    if (lane < 16) red2[wv][lane] = s;
    __syncthreads();

    if (tid < 16) {
        float tot = (red2[0][tid] + red2[1][tid]) + (red2[2][tid] + red2[3][tid]);
        tot *= pre;
        float n2 = tot * tot;
        n2 += __shfl_xor(n2, 1);
        n2 += __shfl_xor(n2, 2);
        n2 += __shfl_xor(n2, 4);
        n2 += __shfl_xor(n2, 8);
        const float n     = sqrtf(n2);
        const float scale = n2 / ((1.f + n2) * (n + 1e-8f));
        const float o_    = scale * tot;
        const int idx = g2 * D_ + tid;
        if (mode == 0)      { v_buf[idx] = o_;  out[idx]  = kscale * o_; }
        else if (mode == 1) { v_buf[idx] += o_; out[idx] += kscale * o_; }
        else                {                   out[idx] += kscale * o_; }
    }
}

// ---------------------------------------------------------------------------
extern "C" void kernel_launch(void* const* d_in, const int* in_sizes, int n_in,
                              void* d_out, int out_size, void* d_ws, size_t ws_size,
                              hipStream_t stream)
{
    const float* x = (const float*)d_in[0];   // [128,4608,8]
    const float* w = (const float*)d_in[1];   // [10,4608,16,8]
    float* out   = (float*)d_out;             // [128,10,16]
    float* parts = (float*)d_ws;                          // 32*80KB = 2.62 MB
    float* v_buf = parts + (long)NIB * PSET;              // 80 KB
    _Float16* pw = (_Float16*)(v_buf + B_ * O_ * D_);     // 11.8 MB P frag image

    prep_kernel<<<NCHUNKS, 256, 0, stream>>>(w, pw);

    // iter 0: c = 1/10 uniform (folded via pre=0.1)
    pass_kernel<0><<<256, 512, 0, stream>>>(x, pw, v_buf, parts);
    reduce_squash<<<1280, 256, 0, stream>>>(parts, v_buf, out, 0.3f, 0.1f, 0);

    // iter 1: b1 = <out0, xh>
    pass_kernel<1><<<256, 512, 0, stream>>>(x, pw, v_buf, parts);
    reduce_squash<<<1280, 256, 0, stream>>>(parts, v_buf, out, 0.3f, 1.0f, 1);

    // iter 2: b2 = <out0 + out1, xh>
    pass_kernel<1><<<256, 512, 0, stream>>>(x, pw, v_buf, parts);
    reduce_squash<<<1280, 256, 0, stream>>>(parts, v_buf, out, 0.4f, 1.0f, 2);
}

// Round 16
// 61.511 us; speedup vs baseline: 1.1533x; 1.0700x over previous
//
#include <hip/hip_runtime.h>

#define B_    128
#define I_    4608
#define O_    10
#define D_    16
#define NCHUNKS 2304      // I_/2
#define NIB   32          // i-blocks; 144 i = 72 chunks each
#define CPB   72          // chunks per i-block: 72/8 waves = 9 chunks/wave, no tail
#define CHH   2560        // halves per prepped chunk: 5 p * 64 lane * 8 (P image only)
#define PSET  20480       // floats per partial set (128*10*16)

typedef _Float16 f16x2 __attribute__((ext_vector_type(2)));
typedef _Float16 f16x4 __attribute__((ext_vector_type(4)));
typedef _Float16 f16x8 __attribute__((ext_vector_type(8)));
typedef float    f32x4 __attribute__((ext_vector_type(4)));
typedef __fp16   pk16x2 __attribute__((ext_vector_type(2)));
typedef unsigned int uint2v __attribute__((ext_vector_type(2)));

__device__ __forceinline__ f16x4 pack4(float a, float b, float c, float d) {
    union { f16x4 v; pk16x2 p[2]; } u;
    u.p[0] = __builtin_amdgcn_cvt_pkrtz(a, b);
    u.p[1] = __builtin_amdgcn_cvt_pkrtz(c, d);
    return u.v;
}
__device__ __forceinline__ f16x2 splat_h2(float a) {
    union { f16x2 v; pk16x2 p; } u;
    u.p = __builtin_amdgcn_cvt_pkrtz(a, a);
    return u.v;
}

// ---------------------------------------------------------------------------
// MFMA routing pass. Grid 256 = 32 i-blocks x 8 b-groups (16 b each),
// XCD-grouped, 1 block/CU, 9 chunks/wave exactly (R15 geometry).
// MODE 0 (prep-fused): reads raw fp32 W per chunk — coalesced: for fixed o
//   the wave's 64 lanes exactly cover the 1 KB slab W[o][2c..2c+1][*][*]
//   (lane groups g=0..3 <-> (iloc,kq) pairs). Packs P-frags in-register
//   (same cvt_pkrtz as the old prep -> bit-identical), applies, and the
//   bg==0 blocks store the f16 frags to pw for passes 1/2.
// MODE 1: reads pw f16 (R10/R15-verified); logits: Wt frag via identity-MFMA
//   transpose, u = mfma(Wt, v), bd = in-lane dot + permlane32_swap, softmax.
// End: 3-step LDS tree over waves -> parts[ib].
// ---------------------------------------------------------------------------
template<int MODE>
__global__ __launch_bounds__(512, 2)
void pass_kernel(const float* __restrict__ x,      // [128][4608][8]
                 const float* __restrict__ w,      // [10][4608][16][8] (MODE 0)
                 _Float16* __restrict__ pwW,       // pw write (MODE 0, bg==0)
                 const _Float16* __restrict__ pw,  // pw read (MODE 1)
                 const float* __restrict__ v,      // [128][10][16]
                 float* __restrict__ parts)        // [NIB][128][10][16]
{
    __shared__ float red[4 * 2560];   // 40 KB

    const int tid  = threadIdx.x;
    const int lane = tid & 63;
    const int wv   = tid >> 6;
    const int bl   = lane & 15;
    const int g    = lane >> 4;
    const int u    = blockIdx.x;
    const int xcd  = u & 7, s = u >> 3;            // s: 0..31
    const int ib   = xcd * 4 + (s & 3);            // same-XCD blocks share ib range
    const int bg   = s >> 2;                       // 0..7
    const int c0   = ib * CPB;
    const int iloc = g & 1, kq = g >> 1;
    const int b0   = bg * 16 + bl;
    const bool wrt = (MODE == 0) && (bg == 0);     // pw writer blocks

    // identity B-frag: I[K=4g+j][col=bl] = (4g+j == bl)
    f16x4 idf;
#pragma unroll
    for (int j = 0; j < 4; ++j) idf[j] = (_Float16)((bl == 4 * g + j) ? 1.f : 0.f);

    f16x4 vf[O_];
    if (MODE == 1) {
#pragma unroll
        for (int o = 0; o < O_; ++o) {
            const float4 vv = *(const float4*)(v + ((long)b0 * O_ + o) * D_ + g * 4);
            vf[o] = pack4(vv.x, vv.y, vv.z, vv.w);
        }
    }

    f32x4 S[O_];
#pragma unroll
    for (int o = 0; o < O_; ++o) S[o] = (f32x4)(0.f);

    const long lofs = (long)lane * 8;
    const int  wofs = bl * 8 + kq * 4;             // within W[o][i]: d*8 + k
    auto fragp = [&](int c, int p) {
        return (const f16x8*)(pw + (long)c * CHH + p * 512 + lofs);
    };
    auto xp = [&](int c) {
        return (const float4*)(x + ((long)b0 * I_ + 2 * c + iloc) * 8 + kq * 4);
    };
    // MODE 0: gather chunk c's P-frags straight from fp32 W (coalesced per o)
    auto wload = [&](int c, f16x8 (&f)[5]) {
        const long iofs = (long)(2 * c + iloc) * 128 + wofs;
#pragma unroll
        for (int p = 0; p < 5; ++p) {
            const float4 w0 = *(const float4*)(w + (long)(2 * p)     * (I_ * 128) + iofs);
            const float4 w1 = *(const float4*)(w + (long)(2 * p + 1) * (I_ * 128) + iofs);
            union { f16x8 v8; f16x4 h[2]; } u2;
            u2.h[0] = pack4(w0.x, w0.y, w0.z, w0.w);
            u2.h[1] = pack4(w1.x, w1.y, w1.z, w1.w);
            f[p] = u2.v8;
        }
    };

    int c = c0 + wv;
    f16x8 f1[5];
    float4 xqC, xqN;
    if (MODE == 0) wload(c, f1);
    else {
#pragma unroll
        for (int p = 0; p < 5; ++p) f1[p] = *fragp(c, p);
    }
    xqC = *xp(c);

    for (int t5 = 0; t5 < 9; ++t5) {
        int cn = c + 8; if (cn > NCHUNKS - 1) cn = NCHUNKS - 1;
        xqN = *xp(cn);

        float cs[O_];
        if (MODE == 1) {
            // logits: Wt = transpose(P) via identity MFMA; u = Wt x v;
            // bd = sum_k u*x (in-lane + permlane32_swap); softmax over o
#pragma unroll
            for (int p = 0; p < 5; ++p) {
                f16x4 pe, po;
                pe[0]=f1[p][0]; pe[1]=f1[p][1]; pe[2]=f1[p][2]; pe[3]=f1[p][3];
                po[0]=f1[p][4]; po[1]=f1[p][5]; po[2]=f1[p][6]; po[3]=f1[p][7];
                const f32x4 te = __builtin_amdgcn_mfma_f32_16x16x16f16(pe, idf, (f32x4)(0.f), 0, 0, 0);
                const f32x4 to = __builtin_amdgcn_mfma_f32_16x16x16f16(po, idf, (f32x4)(0.f), 0, 0, 0);
                const f16x4 ae = pack4(te[0], te[1], te[2], te[3]);
                const f16x4 ao = pack4(to[0], to[1], to[2], to[3]);
                const f32x4 ua = __builtin_amdgcn_mfma_f32_16x16x16f16(ae, vf[2*p],   (f32x4)(0.f), 0, 0, 0);
                const f32x4 ub = __builtin_amdgcn_mfma_f32_16x16x16f16(ao, vf[2*p+1], (f32x4)(0.f), 0, 0, 0);
                float d0 = ua[0] * xqC.x; d0 = fmaf(ua[1], xqC.y, d0);
                d0 = fmaf(ua[2], xqC.z, d0); d0 = fmaf(ua[3], xqC.w, d0);
                float d1 = ub[0] * xqC.x; d1 = fmaf(ub[1], xqC.y, d1);
                d1 = fmaf(ub[2], xqC.z, d1); d1 = fmaf(ub[3], xqC.w, d1);
                cs[2*p] = d0; cs[2*p+1] = d1;
            }
            float ssum = 0.f;
#pragma unroll
            for (int o = 0; o < O_; ++o) {
                const unsigned int tt = __float_as_uint(cs[o]);
                const uint2v sw = __builtin_amdgcn_permlane32_swap(tt, tt, false, false);
                const float e = __expf(__uint_as_float(sw[0]) + __uint_as_float(sw[1]));
                cs[o] = e; ssum += e;
            }
            const float inv = 1.f / ssum;
#pragma unroll
            for (int o = 0; o < O_; ++o) cs[o] *= inv;
        }

        union F4 { f16x4 v; f16x2 h[2]; };
        F4 xh;
        xh.v = pack4(xqC.x, xqC.y, xqC.z, xqC.w);
#pragma unroll
        for (int p = 0; p < 5; ++p) {
            f16x4 pe, po;
            pe[0]=f1[p][0]; pe[1]=f1[p][1]; pe[2]=f1[p][2]; pe[3]=f1[p][3];
            po[0]=f1[p][4]; po[1]=f1[p][5]; po[2]=f1[p][6]; po[3]=f1[p][7];
            F4 ye, yo;
            if (MODE == 0) { ye = xh; yo = xh; }
            else {
                const f16x2 ce = splat_h2(cs[2*p]);
                const f16x2 co = splat_h2(cs[2*p+1]);
                ye.h[0] = xh.h[0] * ce; ye.h[1] = xh.h[1] * ce;
                yo.h[0] = xh.h[0] * co; yo.h[1] = xh.h[1] * co;
            }
            S[2*p]   = __builtin_amdgcn_mfma_f32_16x16x16f16(pe, ye.v, S[2*p],   0, 0, 0);
            S[2*p+1] = __builtin_amdgcn_mfma_f32_16x16x16f16(po, yo.v, S[2*p+1], 0, 0, 0);
        }

        if (MODE == 0) {
            if (wrt) {   // persist chunk c's frags for passes 1/2 (written once)
#pragma unroll
                for (int p = 0; p < 5; ++p)
                    *(f16x8*)(pwW + (long)c * CHH + p * 512 + lofs) = f1[p];
            }
            wload(cn, f1);
        } else {
#pragma unroll
            for (int p = 0; p < 5; ++p) f1[p] = *fragp(cn, p);
        }
        xqC = xqN;
        c += 8;
    }

    // ---- inter-wave tree reduction (waves covered disjoint chunks) ----
    auto slot = [&](int ww, int o) {
        return &red[ww * 2560 + o * 256 + lane * 4];
    };
#define TREE_WR(WSRC)                                                       \
    if (wv >= WSRC && wv < 2 * WSRC) {                                      \
        _Pragma("unroll") for (int o = 0; o < O_; ++o)                      \
            *(f32x4*)slot(wv - WSRC, o) = S[o];                             \
    }                                                                       \
    __syncthreads();                                                        \
    if (wv < WSRC) {                                                        \
        _Pragma("unroll") for (int o = 0; o < O_; ++o)                      \
            S[o] += *(f32x4*)slot(wv, o);                                   \
    }                                                                       \
    __syncthreads();

    TREE_WR(4)
    TREE_WR(2)
    TREE_WR(1)
#undef TREE_WR

    if (wv == 0) {
#pragma unroll
        for (int o = 0; o < O_; ++o) {
            float* pp = parts + (long)ib * PSET + ((long)b0 * O_ + o) * D_ + g * 4;
            *(f32x4*)pp = S[o];
        }
    }
}

// ---------------------------------------------------------------------------
// Reduce 32 partial sets -> s[b,o,d]; squash over d; update v_buf / out.
// Grid 1280 (one block per (b,o)).  (R15-verified)
// ---------------------------------------------------------------------------
__global__ __launch_bounds__(256)
void reduce_squash(const float* __restrict__ parts, float* __restrict__ v_buf,
                   float* __restrict__ out, float kscale, float pre, int mode)
{
    __shared__ float red2[4][16];
    const int tid  = threadIdx.x;
    const int lane = tid & 63;
    const int wv   = tid >> 6;
    const int g2   = blockIdx.x;        // (b*O + o)
    const int pg   = tid >> 4;          // 0..15
    const int d    = tid & 15;

    float s = 0.f;
#pragma unroll
    for (int k = 0; k < 2; ++k)
        s += parts[(long)(pg * 2 + k) * PSET + g2 * D_ + d];

    s += __shfl_xor(s, 16);
    s += __shfl_xor(s, 32);
    if (lane < 16) red2[wv][lane] = s;
    __syncthreads();

    if (tid < 16) {
        float tot = (red2[0][tid] + red2[1][tid]) + (red2[2][tid] + red2[3][tid]);
        tot *= pre;
        float n2 = tot * tot;
        n2 += __shfl_xor(n2, 1);
        n2 += __shfl_xor(n2, 2);
        n2 += __shfl_xor(n2, 4);
        n2 += __shfl_xor(n2, 8);
        const float n     = sqrtf(n2);
        const float scale = n2 / ((1.f + n2) * (n + 1e-8f));
        const float o_    = scale * tot;
        const int idx = g2 * D_ + tid;
        if (mode == 0)      { v_buf[idx] = o_;  out[idx]  = kscale * o_; }
        else if (mode == 1) { v_buf[idx] += o_; out[idx] += kscale * o_; }
        else                {                   out[idx] += kscale * o_; }
    }
}

// ---------------------------------------------------------------------------
extern "C" void kernel_launch(void* const* d_in, const int* in_sizes, int n_in,
                              void* d_out, int out_size, void* d_ws, size_t ws_size,
                              hipStream_t stream)
{
    const float* x = (const float*)d_in[0];   // [128,4608,8]
    const float* w = (const float*)d_in[1];   // [10,4608,16,8]
    float* out   = (float*)d_out;             // [128,10,16]
    float* parts = (float*)d_ws;                          // 32*80KB = 2.62 MB
    float* v_buf = parts + (long)NIB * PSET;              // 80 KB
    _Float16* pw = (_Float16*)(v_buf + B_ * O_ * D_);     // 11.8 MB P frag image

    // iter 0: c = 1/10 uniform (pre=0.1 in reduce); prep fused (emits pw)
    pass_kernel<0><<<256, 512, 0, stream>>>(x, w, pw, pw, v_buf, parts);
    reduce_squash<<<1280, 256, 0, stream>>>(parts, v_buf, out, 0.3f, 0.1f, 0);

    // iter 1: b1 = <out0, xh>
    pass_kernel<1><<<256, 512, 0, stream>>>(x, w, pw, pw, v_buf, parts);
    reduce_squash<<<1280, 256, 0, stream>>>(parts, v_buf, out, 0.3f, 1.0f, 1);

    // iter 2: b2 = <out0 + out1, xh>
    pass_kernel<1><<<256, 512, 0, stream>>>(x, w, pw, pw, v_buf, parts);
    reduce_squash<<<1280, 256, 0, stream>>>(parts, v_buf, out, 0.4f, 1.0f, 2);
}